// Round 5
// baseline (600.598 us; speedup 1.0000x reference)
//
#include <hip/hip_runtime.h>
#include <math.h>

#define LSEQ 624
#define NPG_C 1249
#define BATCH_C 64
#define NROWS (BATCH_C*LSEQ)          // 39936
#define N_NODES_C 79936
#define N_EDGES_C 639488
#define DIP 1160
#define DIN 512
#define CDIM 640
#define NH 8
#define HD 64
#define DS 64
#define CAP 96
#define TCH 48
#define NCHK 13

// workspace layout (float offsets)
#define OFF_CHK   0            // 39936*16 = 638976
#define OFF_WF    638976       // 16*1160 = 18560
#define OFF_BF    657536       // 1160
#define OFF_WOP   658944       // 512*16 = 8192
#define OFF_BOP   667136       // 16
#define OFF_XBC   667392       // 39936*640 = 25559040  (reused as slots after k_carry)
#define OFF_DTV   26226432     // 39936*8              (reused as cnt after k_carry)
#define OFF_EV    26545920     // 39936*8  (log-dA per row/head)
#define OFF_YS    26865408     // 39936*512 = 20447232
#define OFF_FEAT  47312640     // 79936*16 = 1278976
#define OFF_AGG   48591616     // 79936*128 = 10231808 (Gm + ecum aliased here until k_agg)
#define OFF_ECUM  (OFF_AGG + 2000000)  // 39936*8 = 319488, inside agg region after Gm
// total 58823424 floats = 235.3 MB

__device__ __forceinline__ float siluf(float x) {
    return x / (1.f + __expf(-x));
}

// gather check-node rows
__global__ void k_gather(const float* __restrict__ ni, float* __restrict__ chk) {
    int gid = blockIdx.x * 256 + threadIdx.x;
    if (gid >= NROWS * 16) return;
    int row = gid >> 4, k = gid & 15;
    int node = (row / LSEQ) * NPG_C + (row % LSEQ);
    chk[gid] = ni[node * 16 + k];
}

// fused weights
__global__ void k_fusew(const float* __restrict__ We, const float* __restrict__ be,
                        const float* __restrict__ Wi, const float* __restrict__ bi,
                        const float* __restrict__ Wo, const float* __restrict__ bo,
                        const float* __restrict__ Wp, const float* __restrict__ bp,
                        float* __restrict__ Wf, float* __restrict__ bf,
                        float* __restrict__ Wop, float* __restrict__ bop) {
    int id = blockIdx.x * 256 + threadIdx.x;
    if (id < 16 * DIP) {
        int i = id / DIP, j = id % DIP;
        float s = 0.f;
        for (int k = 0; k < 256; k++) s = fmaf(We[i * 256 + k], Wi[k * DIP + j], s);
        Wf[id] = s;
    } else if (id < 16 * DIP + DIP) {
        int j = id - 16 * DIP;
        float s = bi[j];
        for (int k = 0; k < 256; k++) s = fmaf(be[k], Wi[k * DIP + j], s);
        bf[j] = s;
    } else if (id < 16 * DIP + DIP + DIN * 16) {
        int id2 = id - (16 * DIP + DIP);
        int c = id2 >> 4, o = id2 & 15;
        float s = 0.f;
        for (int k = 0; k < 256; k++) s = fmaf(Wo[c * 256 + k], Wp[k * 16 + o], s);
        Wop[id2] = s;
    } else if (id < 16 * DIP + DIP + DIN * 16 + 16) {
        int o = id - (16 * DIP + DIP + DIN * 16);
        float s = bp[o];
        for (int k = 0; k < 256; k++) s = fmaf(bo[k], Wp[k * 16 + o], s);
        bop[o] = s;
    }
}

// fused in_proj(xBC cols) + causal depthwise conv + silu
__global__ __launch_bounds__(320) void k_conv(const float* __restrict__ chk,
        const float* __restrict__ Wf, const float* __restrict__ bf,
        const float* __restrict__ cw, const float* __restrict__ cb,
        float* __restrict__ xBCc) {
    int c = blockIdx.x * 320 + threadIdx.x;     // 0..639
    int t0 = blockIdx.y * 78;
    int b = blockIdx.z;
    float w[16];
#pragma unroll
    for (int k = 0; k < 16; k++) w[k] = Wf[k * DIP + DIN + c];
    float bfx = bf[DIN + c];
    float k0 = cw[c * 4 + 0], k1 = cw[c * 4 + 1], k2 = cw[c * 4 + 2], k3 = cw[c * 4 + 3];
    float cbv = cb[c];
    const float* crow = chk + (size_t)(b * LSEQ) * 16;
    float* out = xBCc + (size_t)(b * LSEQ) * CDIM + c;

    float w0 = 0.f, w1 = 0.f, w2 = 0.f;
#pragma unroll
    for (int d = 3; d >= 1; d--) {
        int tau = t0 - d;
        float s = 0.f;
        if (tau >= 0) {
            s = bfx;
            const float* cr = crow + tau * 16;
#pragma unroll
            for (int k = 0; k < 16; k++) s = fmaf(cr[k], w[k], s);
        }
        if (d == 3) w0 = s; else if (d == 2) w1 = s; else w2 = s;
    }
    for (int t = t0; t < t0 + 78; t++) {
        const float* cr = crow + t * 16;
        float w3 = bfx;
#pragma unroll
        for (int k = 0; k < 16; k++) w3 = fmaf(cr[k], w[k], w3);
        float a = fmaf(k0, w0, fmaf(k1, w1, fmaf(k2, w2, fmaf(k3, w3, cbv))));
        out[(size_t)t * CDIM] = siluf(a);
        w0 = w1; w1 = w2; w2 = w3;
    }
}

// dt head columns: dtv = softplus(...), ev = -exp(A_log)*dtv  (= log dA)
__global__ void k_dt(const float* __restrict__ chk, const float* __restrict__ Wf,
                     const float* __restrict__ bf, const float* __restrict__ A_log,
                     const float* __restrict__ dt_bias,
                     float* __restrict__ dtv, float* __restrict__ ev) {
    int id = blockIdx.x * 256 + threadIdx.x;
    if (id >= NROWS * NH) return;
    int row = id >> 3, h = id & 7;
    const float* cr = chk + (size_t)row * 16;
    float s = bf[DIN + CDIM + h];
#pragma unroll
    for (int k = 0; k < 16; k++) s = fmaf(cr[k], Wf[k * DIP + DIN + CDIM + h], s);
    s += dt_bias[h];
    float sp = (s > 20.f) ? s : log1pf(__expf(s));
    dtv[id] = sp;
    ev[id] = -__expf(A_log[h]) * sp;
}

// within-chunk inclusive prefix of ev: one wave per (b,chunk,head) segment
// segments = 64*13*8 = 6656; 4 per block
__global__ __launch_bounds__(256) void k_ecum(const float* __restrict__ ev,
        float* __restrict__ ecum) {
    int s = blockIdx.x * 4 + (threadIdx.x >> 6);
    int lane = threadIdx.x & 63;
    int h = s & 7;
    int cb = s >> 3;
    int c = cb % NCHK, b = cb / NCHK;
    int r0 = b * LSEQ + c * TCH;
    float v = 0.f;
    if (lane < TCH) v = ev[(size_t)(r0 + lane) * NH + h];
#pragma unroll
    for (int off = 1; off < 64; off <<= 1) {
        float u = __shfl_up(v, off);
        if (lane >= off) v += u;
    }
    if (lane < TCH) ecum[(size_t)(r0 + lane) * NH + h] = v;
}

// G[t][s] = C_t . B_s per (b,chunk).  grid (13, 64), 256 thr.
__global__ __launch_bounds__(256) void k_gmat(const float* __restrict__ xBCc,
        float* __restrict__ Gm) {
    int c = blockIdx.x, b = blockIdx.y;
    int tid = threadIdx.x;
    int bs = b * LSEQ;
    __shared__ __align__(16) float sBC[TCH * 132];   // [t][0..63]=B, [t][64..127]=C
#pragma unroll
    for (int j = 0; j < 6; j++) {
        int g = j * 256 + tid;
        int f = g * 4;
        int t = f >> 7, col = f & 127;
        float4 v = *(const float4*)(xBCc + (size_t)(bs + c * TCH + t) * CDIM + 512 + col);
        *(float4*)&sBC[t * 132 + col] = v;
    }
    __syncthreads();
    int t0 = (tid >> 4) * 3, s0 = (tid & 15) * 3;
    float acc[3][3];
#pragma unroll
    for (int i = 0; i < 3; i++)
#pragma unroll
        for (int j = 0; j < 3; j++) acc[i][j] = 0.f;
    for (int k = 0; k < 64; k++) {
        float c0 = sBC[(t0 + 0) * 132 + 64 + k];
        float c1 = sBC[(t0 + 1) * 132 + 64 + k];
        float c2 = sBC[(t0 + 2) * 132 + 64 + k];
        float b0 = sBC[(s0 + 0) * 132 + k];
        float b1 = sBC[(s0 + 1) * 132 + k];
        float b2 = sBC[(s0 + 2) * 132 + k];
        acc[0][0] = fmaf(c0, b0, acc[0][0]); acc[0][1] = fmaf(c0, b1, acc[0][1]); acc[0][2] = fmaf(c0, b2, acc[0][2]);
        acc[1][0] = fmaf(c1, b0, acc[1][0]); acc[1][1] = fmaf(c1, b1, acc[1][1]); acc[1][2] = fmaf(c1, b2, acc[1][2]);
        acc[2][0] = fmaf(c2, b0, acc[2][0]); acc[2][1] = fmaf(c2, b1, acc[2][1]); acc[2][2] = fmaf(c2, b2, acc[2][2]);
    }
    size_t gb = (size_t)(b * NCHK + c) * (TCH * TCH);
#pragma unroll
    for (int i = 0; i < 3; i++)
#pragma unroll
        for (int j = 0; j < 3; j++)
            Gm[gb + (t0 + i) * TCH + (s0 + j)] = acc[i][j];
}

// intra-chunk: Y = M @ X + dsk*X, M[t][s] = exp(E[t]-E[s])*dt_s*G[t][s] (s<=t)
// grid (13, 8, 64) = (chunk, head, b), 256 thr
__global__ __launch_bounds__(256) void k_intra(const float* __restrict__ xBCc,
        const float* __restrict__ Gm, const float* __restrict__ dtv,
        const float* __restrict__ ecum, const float* __restrict__ Dskip,
        float* __restrict__ ysb) {
    int c = blockIdx.x, head = blockIdx.y, b = blockIdx.z;
    int tid = threadIdx.x;
    int bs = b * LSEQ;
    int r0 = bs + c * TCH;
    __shared__ __align__(16) float sX[TCH * 64];
    __shared__ float sM[TCH * TCH];
    __shared__ float sE[TCH], sdt[TCH];

#pragma unroll
    for (int j = 0; j < 3; j++) {
        int g = j * 256 + tid;
        int f = g * 4;
        int t = f >> 6, col = f & 63;
        float4 v = *(const float4*)(xBCc + (size_t)(r0 + t) * CDIM + head * HD + col);
        *(float4*)&sX[t * 64 + col] = v;
    }
    if (tid < TCH) {
        sE[tid] = ecum[(size_t)(r0 + tid) * NH + head];
        sdt[tid] = dtv[(size_t)(r0 + tid) * NH + head];
    }
    __syncthreads();
    size_t gb = (size_t)(b * NCHK + c) * (TCH * TCH);
#pragma unroll
    for (int k = 0; k < 9; k++) {
        int id = k * 256 + tid;
        int t = id / TCH, s = id - t * TCH;
        float g = Gm[gb + id];
        sM[id] = (s <= t) ? __expf(sE[t] - sE[s]) * sdt[s] * g : 0.f;
    }
    __syncthreads();

    int t0 = (tid >> 4) * 3, p4 = (tid & 15) * 4;
    float4 a0 = {0,0,0,0}, a1 = {0,0,0,0}, a2 = {0,0,0,0};
    for (int s = 0; s < TCH; s++) {
        float m0 = sM[(t0 + 0) * TCH + s];
        float m1 = sM[(t0 + 1) * TCH + s];
        float m2 = sM[(t0 + 2) * TCH + s];
        float4 xv = *(const float4*)&sX[s * 64 + p4];
        a0.x = fmaf(m0, xv.x, a0.x); a0.y = fmaf(m0, xv.y, a0.y);
        a0.z = fmaf(m0, xv.z, a0.z); a0.w = fmaf(m0, xv.w, a0.w);
        a1.x = fmaf(m1, xv.x, a1.x); a1.y = fmaf(m1, xv.y, a1.y);
        a1.z = fmaf(m1, xv.z, a1.z); a1.w = fmaf(m1, xv.w, a1.w);
        a2.x = fmaf(m2, xv.x, a2.x); a2.y = fmaf(m2, xv.y, a2.y);
        a2.z = fmaf(m2, xv.z, a2.z); a2.w = fmaf(m2, xv.w, a2.w);
    }
    float dsk = Dskip[head];
    float4 accs[3] = {a0, a1, a2};
#pragma unroll
    for (int i = 0; i < 3; i++) {
        float4 xo = *(const float4*)&sX[(t0 + i) * 64 + p4];
        float4 o;
        o.x = fmaf(dsk, xo.x, accs[i].x);
        o.y = fmaf(dsk, xo.y, accs[i].y);
        o.z = fmaf(dsk, xo.z, accs[i].z);
        o.w = fmaf(dsk, xo.w, accs[i].w);
        *(float4*)&ysb[(size_t)(r0 + t0 + i) * DIN + head * HD + p4] = o;
    }
}

// inter-chunk carry + y-correction, p-split in 2 halves of 32.
// grid (8, 64, 2); 256 thr. State per thread 2p x 4n; y-GEMM 3t x 2p.
#define PH 32
__global__ __launch_bounds__(256, 4) void k_carry(const float* __restrict__ xBCc,
        const float* __restrict__ dtv, const float* __restrict__ ecum,
        float* __restrict__ ysb) {
    int head = blockIdx.x, b = blockIdx.y;
    int pbase = blockIdx.z * PH;
    int tid = threadIdx.x;
    int bs = b * LSEQ;
    __shared__ __align__(16) float sX[TCH * PH];      // 1536
    __shared__ __align__(16) float sB[TCH * 64];      // 3072
    __shared__ __align__(16) float sC[TCH * 64];      // 3072
    __shared__ __align__(16) float hbuf[64 * 34];     // 2176  [n][p] pad 34
    __shared__ float sW[TCH], sDt[TCH];

    int i2 = (tid >> 4) * 2;   // p (state)
    int j4 = (tid & 15) * 4;   // n (state)
    int t0 = (tid >> 4) * 3;   // t (y-GEMM)
    int p2 = (tid & 15) * 2;   // p (y-GEMM)

    float h[2][4];
#pragma unroll
    for (int i = 0; i < 2; i++)
#pragma unroll
        for (int j = 0; j < 4; j++) h[i][j] = 0.f;

    float4 rX0, rX1, rB[3], rC[3];
    float rEc = 0.f, rDt = 0.f, rEcL = 0.f;

#define CARRY_ISSUE(cc)                                                             \
    {                                                                               \
        int r0i = bs + (cc) * TCH;                                                  \
        {   int f = 4 * tid; int t = f >> 5; int col = f & 31;                      \
            rX0 = *(const float4*)(xBCc + (size_t)(r0i + t) * CDIM + head * HD + pbase + col); \
            if (tid < 128) {                                                        \
                int f2 = 1024 + 4 * tid; int t2 = f2 >> 5; int col2 = f2 & 31;      \
                rX1 = *(const float4*)(xBCc + (size_t)(r0i + t2) * CDIM + head * HD + pbase + col2); \
            }                                                                       \
        }                                                                           \
        _Pragma("unroll")                                                           \
        for (int jj = 0; jj < 3; jj++) {                                            \
            int g = jj * 256 + tid; int f = 4 * g; int t = f >> 6; int col = f & 63;\
            rB[jj] = *(const float4*)(xBCc + (size_t)(r0i + t) * CDIM + 512 + col); \
            rC[jj] = *(const float4*)(xBCc + (size_t)(r0i + t) * CDIM + 576 + col); \
        }                                                                           \
        if (tid < TCH) { rEc = ecum[(size_t)(r0i + tid) * NH + head];               \
                         rDt = dtv[(size_t)(r0i + tid) * NH + head]; }              \
        rEcL = ecum[(size_t)(r0i + TCH - 1) * NH + head];                           \
    }

    CARRY_ISSUE(0);
    for (int c = 0; c < NCHK; c++) {
        int r0 = bs + c * TCH;
        __syncthreads();                       // prev compute done; LDS reusable
        float eL = __expf(rEcL);
        *(float4*)&sX[4 * tid] = rX0;
        if (tid < 128) *(float4*)&sX[1024 + 4 * tid] = rX1;
#pragma unroll
        for (int jj = 0; jj < 3; jj++) {
            int g = jj * 256 + tid;
            *(float4*)&sB[4 * g] = rB[jj];
            *(float4*)&sC[4 * g] = rC[jj];
        }
        if (tid < TCH) { sW[tid] = __expf(rEcL - rEc) * rDt; sDt[tid] = __expf(rEc); }
        // publish h_start
#pragma unroll
        for (int jj = 0; jj < 4; jj++)
            *(float2*)&hbuf[(j4 + jj) * 34 + i2] = make_float2(h[0][jj], h[1][jj]);
        __syncthreads();
        if (c + 1 < NCHK) CARRY_ISSUE(c + 1);  // in flight during compute

        if (c > 0) {
            float2 a0 = {0,0}, a1 = {0,0}, a2 = {0,0};
            for (int k4 = 0; k4 < 64; k4 += 4) {
                float4 cv0 = *(const float4*)&sC[(t0 + 0) * 64 + k4];
                float4 cv1 = *(const float4*)&sC[(t0 + 1) * 64 + k4];
                float4 cv2 = *(const float4*)&sC[(t0 + 2) * 64 + k4];
                float2 h0 = *(const float2*)&hbuf[(k4 + 0) * 34 + p2];
                float2 h1 = *(const float2*)&hbuf[(k4 + 1) * 34 + p2];
                float2 h2 = *(const float2*)&hbuf[(k4 + 2) * 34 + p2];
                float2 h3 = *(const float2*)&hbuf[(k4 + 3) * 34 + p2];
                a0.x = fmaf(cv0.x,h0.x,a0.x); a0.y = fmaf(cv0.x,h0.y,a0.y);
                a0.x = fmaf(cv0.y,h1.x,a0.x); a0.y = fmaf(cv0.y,h1.y,a0.y);
                a0.x = fmaf(cv0.z,h2.x,a0.x); a0.y = fmaf(cv0.z,h2.y,a0.y);
                a0.x = fmaf(cv0.w,h3.x,a0.x); a0.y = fmaf(cv0.w,h3.y,a0.y);
                a1.x = fmaf(cv1.x,h0.x,a1.x); a1.y = fmaf(cv1.x,h0.y,a1.y);
                a1.x = fmaf(cv1.y,h1.x,a1.x); a1.y = fmaf(cv1.y,h1.y,a1.y);
                a1.x = fmaf(cv1.z,h2.x,a1.x); a1.y = fmaf(cv1.z,h2.y,a1.y);
                a1.x = fmaf(cv1.w,h3.x,a1.x); a1.y = fmaf(cv1.w,h3.y,a1.y);
                a2.x = fmaf(cv2.x,h0.x,a2.x); a2.y = fmaf(cv2.x,h0.y,a2.y);
                a2.x = fmaf(cv2.y,h1.x,a2.x); a2.y = fmaf(cv2.y,h1.y,a2.y);
                a2.x = fmaf(cv2.z,h2.x,a2.x); a2.y = fmaf(cv2.z,h2.y,a2.y);
                a2.x = fmaf(cv2.w,h3.x,a2.x); a2.y = fmaf(cv2.w,h3.y,a2.y);
            }
            float2 as[3] = {a0, a1, a2};
#pragma unroll
            for (int i = 0; i < 3; i++) {
                float d = sDt[t0 + i];
                float* yp = ysb + (size_t)(r0 + t0 + i) * DIN + head * HD + pbase + p2;
                float2 y = *(float2*)yp;
                y.x = fmaf(d, as[i].x, y.x);
                y.y = fmaf(d, as[i].y, y.y);
                *(float2*)yp = y;
            }
        }

        // state update: h = eL*h + sum_s sW[s] * X[s][p] * B[s][n]
#pragma unroll
        for (int i = 0; i < 2; i++)
#pragma unroll
            for (int j = 0; j < 4; j++) h[i][j] *= eL;
        for (int s = 0; s < TCH; s++) {
            float w = sW[s];
            float2 xv = *(const float2*)&sX[s * PH + i2];
            float4 bv = *(const float4*)&sB[s * 64 + j4];
            float x0 = w * xv.x, x1 = w * xv.y;
            h[0][0] = fmaf(x0, bv.x, h[0][0]); h[0][1] = fmaf(x0, bv.y, h[0][1]);
            h[0][2] = fmaf(x0, bv.z, h[0][2]); h[0][3] = fmaf(x0, bv.w, h[0][3]);
            h[1][0] = fmaf(x1, bv.x, h[1][0]); h[1][1] = fmaf(x1, bv.y, h[1][1]);
            h[1][2] = fmaf(x1, bv.z, h[1][2]); h[1][3] = fmaf(x1, bv.w, h[1][3]);
        }
    }
#undef CARRY_ISSUE
}

// gate (recompute z, reg weights) + RMSNorm + fused out_proj@proj + scatter.
// 8 rows per block: Wfz in registers, Wop L1-resident across rows.
__global__ __launch_bounds__(256) void k_gate(const float* __restrict__ chk,
        const float* __restrict__ Wf, const float* __restrict__ bf,
        const float* __restrict__ ysb, const float* __restrict__ norm_w,
        const float* __restrict__ Wop, const float* __restrict__ bop,
        float* __restrict__ feat) {
    int row0 = blockIdx.x * 8;
    int tid = threadIdx.x;
    __shared__ float sy[512];
    __shared__ float sred[256];
    __shared__ float swave[4];
    int c1 = tid, c2 = tid + 256;
    float wz1[16], wz2[16];
#pragma unroll
    for (int k = 0; k < 16; k++) {
        wz1[k] = Wf[k * DIP + c1];
        wz2[k] = Wf[k * DIP + c2];
    }
    float zb1 = bf[c1], zb2 = bf[c2];
    float nw1 = norm_w[c1], nw2 = norm_w[c2];
    int o = tid & 15, kg = tid >> 4;
    int wid = tid >> 6, lane = tid & 63;
    for (int r = 0; r < 8; r++) {
        int row = row0 + r;
        const float4* cp = (const float4*)(chk + (size_t)row * 16);
        float4 cA = cp[0], cB = cp[1], cC = cp[2], cD = cp[3];
        float cv[16] = {cA.x,cA.y,cA.z,cA.w, cB.x,cB.y,cB.z,cB.w,
                        cC.x,cC.y,cC.z,cC.w, cD.x,cD.y,cD.z,cD.w};
        float z1 = zb1, z2 = zb2;
#pragma unroll
        for (int k = 0; k < 16; k++) {
            z1 = fmaf(cv[k], wz1[k], z1);
            z2 = fmaf(cv[k], wz2[k], z2);
        }
        float y1 = ysb[(size_t)row * DIN + c1] * siluf(z1);
        float y2 = ysb[(size_t)row * DIN + c2] * siluf(z2);
        float ss = y1 * y1 + y2 * y2;
#pragma unroll
        for (int off = 32; off >= 1; off >>= 1) ss += __shfl_xor(ss, off);
        if (lane == 0) swave[wid] = ss;
        __syncthreads();
        float tot = swave[0] + swave[1] + swave[2] + swave[3];
        float scale = 1.f / sqrtf(tot * (1.f / 512.f) + 1e-5f);
        sy[c1] = y1 * scale * nw1;
        sy[c2] = y2 * scale * nw2;
        __syncthreads();
        float ps = 0.f;
#pragma unroll
        for (int j = 0; j < 32; j++) {
            int k = kg * 32 + j;
            ps = fmaf(sy[k], Wop[k * 16 + o], ps);
        }
        sred[kg * 16 + o] = ps;
        __syncthreads();
        if (tid < 16) {
            float s = bop[tid];
#pragma unroll
            for (int g = 0; g < 16; g++) s += sred[g * 16 + tid];
            int bb = row / LSEQ, t = row % LSEQ;
            feat[(size_t)(bb * NPG_C + t) * 16 + tid] = s;
        }
    }
}

// build per-dst adjacency: cnt (int) + slot list of src ids
__global__ void k_scatter(const int* __restrict__ src, const int* __restrict__ dst,
                          int* __restrict__ cnt, int* __restrict__ slots) {
    int e = blockIdx.x * 256 + threadIdx.x;
    if (e >= N_EDGES_C) return;
    int d = dst[e];
    int pos = atomicAdd(&cnt[d], 1);
    if (pos < CAP) slots[(size_t)d * CAP + pos] = src[e];
}

// dst-centric aggregate: block per node, thread per channel
__global__ __launch_bounds__(128) void k_agg(const int* __restrict__ cnt,
        const int* __restrict__ slots, const float* __restrict__ feat,
        const float* __restrict__ Wm, const float* __restrict__ bm,
        float* __restrict__ agg) {
    int d = blockIdx.x, c = threadIdx.x;
    int deg = cnt[d];
    if (deg > CAP) deg = CAP;
    float w[16];
#pragma unroll
    for (int k = 0; k < 16; k++) w[k] = Wm[k * 128 + c];
    float bmv = bm[c];
    float acc = 0.f;
    const int* sl = slots + (size_t)d * CAP;
    for (int e = 0; e < deg; e++) {
        int s = __builtin_amdgcn_readfirstlane(sl[e]);
        const float4* fr = (const float4*)(feat + (size_t)s * 16);
        float4 f0 = fr[0], f1 = fr[1], f2 = fr[2], f3 = fr[3];
        float m = bmv;
        m = fmaf(f0.x, w[0],  m); m = fmaf(f0.y, w[1],  m);
        m = fmaf(f0.z, w[2],  m); m = fmaf(f0.w, w[3],  m);
        m = fmaf(f1.x, w[4],  m); m = fmaf(f1.y, w[5],  m);
        m = fmaf(f1.z, w[6],  m); m = fmaf(f1.w, w[7],  m);
        m = fmaf(f2.x, w[8],  m); m = fmaf(f2.y, w[9],  m);
        m = fmaf(f2.z, w[10], m); m = fmaf(f2.w, w[11], m);
        m = fmaf(f3.x, w[12], m); m = fmaf(f3.y, w[13], m);
        m = fmaf(f3.z, w[14], m); m = fmaf(f3.w, w[15], m);
        acc += fmaxf(m, 0.f);
    }
    agg[(size_t)d * 128 + c] = acc;
}

// node update MLP + output head, 16 nodes per block
#define UNB 16
__global__ __launch_bounds__(256) void k_upd2(const float* __restrict__ feat,
        const float* __restrict__ agg, const float* __restrict__ Wu,
        const float* __restrict__ bu, const float* __restrict__ Wo2,
        const float* __restrict__ bo2, float* __restrict__ out) {
    int g0 = blockIdx.x * UNB;
    int tid = threadIdx.x;
    __shared__ __align__(16) float sin_[UNB][144];
    __shared__ float part[4][8][2];
    for (int w = tid; w < UNB * 144; w += 256) {
        int node = w / 144, k = w - node * 144;
        sin_[node][k] = (k < 16) ? feat[(size_t)(g0 + node) * 16 + k]
                                 : agg[(size_t)(g0 + node) * 128 + (k - 16)];
    }
    __syncthreads();
    int rr = tid >> 7, c = tid & 127;
    float acc[8];
#pragma unroll
    for (int nn = 0; nn < 8; nn++) acc[nn] = 0.f;
    for (int k0 = 0; k0 < 144; k0 += 4) {
        float wu0 = Wu[(k0 + 0) * 128 + c];
        float wu1 = Wu[(k0 + 1) * 128 + c];
        float wu2 = Wu[(k0 + 2) * 128 + c];
        float wu3 = Wu[(k0 + 3) * 128 + c];
#pragma unroll
        for (int nn = 0; nn < 8; nn++) {
            float4 s4 = *(const float4*)&sin_[rr * 8 + nn][k0];
            acc[nn] = fmaf(s4.x, wu0, acc[nn]);
            acc[nn] = fmaf(s4.y, wu1, acc[nn]);
            acc[nn] = fmaf(s4.z, wu2, acc[nn]);
            acc[nn] = fmaf(s4.w, wu3, acc[nn]);
        }
    }
    float buc = bu[c];
    float w0 = Wo2[c * 2], w1 = Wo2[c * 2 + 1];
    float p[8][2];
#pragma unroll
    for (int nn = 0; nn < 8; nn++) {
        float h = fmaxf(acc[nn] + buc, 0.f);
        p[nn][0] = h * w0;
        p[nn][1] = h * w1;
    }
#pragma unroll
    for (int off = 1; off < 64; off <<= 1) {
#pragma unroll
        for (int nn = 0; nn < 8; nn++) {
            p[nn][0] += __shfl_xor(p[nn][0], off);
            p[nn][1] += __shfl_xor(p[nn][1], off);
        }
    }
    int wv = tid >> 6;
    if ((tid & 63) == 0) {
#pragma unroll
        for (int nn = 0; nn < 8; nn++) {
            part[wv][nn][0] = p[nn][0];
            part[wv][nn][1] = p[nn][1];
        }
    }
    __syncthreads();
    if (tid < 32) {
        int o = tid & 1, nn = (tid >> 1) & 7, r2 = tid >> 4;
        float v = part[r2 * 2 + 0][nn][o] + part[r2 * 2 + 1][nn][o] + bo2[o];
        out[(size_t)(g0 + r2 * 8 + nn) * 2 + o] = v;
    }
}

extern "C" void kernel_launch(void* const* d_in, const int* in_sizes, int n_in,
                              void* d_out, int out_size, void* d_ws, size_t ws_size,
                              hipStream_t stream) {
    const float* node_inputs = (const float*)d_in[0];
    const int*   src_ids     = (const int*)d_in[1];
    const int*   dst_ids     = (const int*)d_in[2];
    const float* W_embed     = (const float*)d_in[3];
    const float* b_embed     = (const float*)d_in[4];
    const float* W_in        = (const float*)d_in[5];
    const float* b_in        = (const float*)d_in[6];
    const float* conv_w      = (const float*)d_in[7];
    const float* conv_b      = (const float*)d_in[8];
    const float* A_log       = (const float*)d_in[9];
    const float* dt_bias     = (const float*)d_in[10];
    const float* D_skip      = (const float*)d_in[11];
    const float* norm_w      = (const float*)d_in[12];
    const float* W_outp      = (const float*)d_in[13];
    const float* b_outp      = (const float*)d_in[14];
    const float* W_proj      = (const float*)d_in[15];
    const float* b_proj      = (const float*)d_in[16];
    const float* W_msg       = (const float*)d_in[17];
    const float* b_msg       = (const float*)d_in[18];
    const float* W_upd       = (const float*)d_in[19];
    const float* b_upd       = (const float*)d_in[20];
    const float* W_out       = (const float*)d_in[21];
    const float* b_out       = (const float*)d_in[22];

    float* ws   = (float*)d_ws;
    float* chk  = ws + OFF_CHK;
    float* Wf   = ws + OFF_WF;
    float* bf   = ws + OFF_BF;
    float* Wop  = ws + OFF_WOP;
    float* bop  = ws + OFF_BOP;
    float* xBCc = ws + OFF_XBC;
    float* dtv  = ws + OFF_DTV;
    float* ev   = ws + OFF_EV;
    float* ecum = ws + OFF_ECUM;
    float* ysb  = ws + OFF_YS;
    float* feat = ws + OFF_FEAT;
    float* agg  = ws + OFF_AGG;
    float* Gm   = ws + OFF_AGG;            // aliases agg (dead until k_agg)
    int*   slots = (int*)(ws + OFF_XBC);   // aliases xBCc (dead after k_carry)
    int*   cnt   = (int*)(ws + OFF_DTV);   // aliases dtv  (dead after k_gate)
    float* out  = (float*)d_out;

    hipMemsetAsync(feat, 0, (size_t)N_NODES_C * 16 * 4, stream);

    k_gather<<<(NROWS * 16 + 255) / 256, 256, 0, stream>>>(node_inputs, chk);
    k_fusew<<<(16 * DIP + DIP + DIN * 16 + 16 + 255) / 256, 256, 0, stream>>>(
        W_embed, b_embed, W_in, b_in, W_outp, b_outp, W_proj, b_proj, Wf, bf, Wop, bop);
    k_conv<<<dim3(2, 8, BATCH_C), 320, 0, stream>>>(chk, Wf, bf, conv_w, conv_b, xBCc);
    k_dt<<<(NROWS * NH + 255) / 256, 256, 0, stream>>>(chk, Wf, bf, A_log, dt_bias, dtv, ev);
    k_ecum<<<(BATCH_C * NCHK * NH) / 4, 256, 0, stream>>>(ev, ecum);
    k_gmat<<<dim3(NCHK, BATCH_C), 256, 0, stream>>>(xBCc, Gm);
    k_intra<<<dim3(NCHK, NH, BATCH_C), 256, 0, stream>>>(xBCc, Gm, dtv, ecum, D_skip, ysb);
    k_carry<<<dim3(NH, BATCH_C, 2), 256, 0, stream>>>(xBCc, dtv, ecum, ysb);
    k_gate<<<NROWS / 8, 256, 0, stream>>>(chk, Wf, bf, ysb, norm_w, Wop, bop, feat);
    // adjacency build (slots/cnt alias regions dead after k_carry/k_gate)
    hipMemsetAsync(cnt, 0, (size_t)N_NODES_C * 4, stream);
    k_scatter<<<(N_EDGES_C + 255) / 256, 256, 0, stream>>>(src_ids, dst_ids, cnt, slots);
    k_agg<<<N_NODES_C, 128, 0, stream>>>(cnt, slots, feat, W_msg, b_msg, agg);
    k_upd2<<<N_NODES_C / UNB, 256, 0, stream>>>(feat, agg, W_upd, b_upd, W_out, b_out, out);
}

// Round 6
// 515.978 us; speedup vs baseline: 1.1640x; 1.1640x over previous
//
#include <hip/hip_runtime.h>
#include <math.h>

#define LSEQ 624
#define NPG_C 1249
#define BATCH_C 64
#define NROWS (BATCH_C*LSEQ)          // 39936
#define N_NODES_C 79936
#define N_EDGES_C 639488
#define DIP 1160
#define DIN 512
#define CDIM 640
#define NH 8
#define HD 64
#define DS 64
#define CAP 96
#define TCH 48
#define NCHK 13

// workspace layout (float offsets)
#define OFF_CHK   0            // 39936*16 = 638976
#define OFF_WF    638976       // 16*1160 = 18560
#define OFF_BF    657536       // 1160
#define OFF_WOP   658944       // 512*16 = 8192
#define OFF_BOP   667136       // 16
#define OFF_XBC   667392       // 39936*640 = 25559040  (reused as slots after k_carry)
#define OFF_DTV   26226432     // 39936*8              (reused as cnt after k_carry)
#define OFF_EV    26545920     // 39936*8  (log-dA per row/head)
#define OFF_YS    26865408     // 39936*512 = 20447232
#define OFF_FEAT  47312640     // 79936*16 = 1278976
#define OFF_AGG   48591616     // 79936*128 = 10231808 (Gm + ecum aliased here until k_agg)
#define OFF_ECUM  (OFF_AGG + 2000000)  // 39936*8 = 319488, inside agg region after Gm
// total 58823424 floats = 235.3 MB

__device__ __forceinline__ float siluf(float x) {
    return x / (1.f + __expf(-x));
}

// gather check-node rows
__global__ void k_gather(const float* __restrict__ ni, float* __restrict__ chk) {
    int gid = blockIdx.x * 256 + threadIdx.x;
    if (gid >= NROWS * 16) return;
    int row = gid >> 4, k = gid & 15;
    int node = (row / LSEQ) * NPG_C + (row % LSEQ);
    chk[gid] = ni[node * 16 + k];
}

// fused weights
__global__ void k_fusew(const float* __restrict__ We, const float* __restrict__ be,
                        const float* __restrict__ Wi, const float* __restrict__ bi,
                        const float* __restrict__ Wo, const float* __restrict__ bo,
                        const float* __restrict__ Wp, const float* __restrict__ bp,
                        float* __restrict__ Wf, float* __restrict__ bf,
                        float* __restrict__ Wop, float* __restrict__ bop) {
    int id = blockIdx.x * 256 + threadIdx.x;
    if (id < 16 * DIP) {
        int i = id / DIP, j = id % DIP;
        float s = 0.f;
        for (int k = 0; k < 256; k++) s = fmaf(We[i * 256 + k], Wi[k * DIP + j], s);
        Wf[id] = s;
    } else if (id < 16 * DIP + DIP) {
        int j = id - 16 * DIP;
        float s = bi[j];
        for (int k = 0; k < 256; k++) s = fmaf(be[k], Wi[k * DIP + j], s);
        bf[j] = s;
    } else if (id < 16 * DIP + DIP + DIN * 16) {
        int id2 = id - (16 * DIP + DIP);
        int c = id2 >> 4, o = id2 & 15;
        float s = 0.f;
        for (int k = 0; k < 256; k++) s = fmaf(Wo[c * 256 + k], Wp[k * 16 + o], s);
        Wop[id2] = s;
    } else if (id < 16 * DIP + DIP + DIN * 16 + 16) {
        int o = id - (16 * DIP + DIP + DIN * 16);
        float s = bp[o];
        for (int k = 0; k < 256; k++) s = fmaf(bo[k], Wp[k * 16 + o], s);
        bop[o] = s;
    }
}

// fused in_proj(xBC cols) + causal depthwise conv + silu
__global__ __launch_bounds__(320) void k_conv(const float* __restrict__ chk,
        const float* __restrict__ Wf, const float* __restrict__ bf,
        const float* __restrict__ cw, const float* __restrict__ cb,
        float* __restrict__ xBCc) {
    int c = blockIdx.x * 320 + threadIdx.x;     // 0..639
    int t0 = blockIdx.y * 78;
    int b = blockIdx.z;
    float w[16];
#pragma unroll
    for (int k = 0; k < 16; k++) w[k] = Wf[k * DIP + DIN + c];
    float bfx = bf[DIN + c];
    float k0 = cw[c * 4 + 0], k1 = cw[c * 4 + 1], k2 = cw[c * 4 + 2], k3 = cw[c * 4 + 3];
    float cbv = cb[c];
    const float* crow = chk + (size_t)(b * LSEQ) * 16;
    float* out = xBCc + (size_t)(b * LSEQ) * CDIM + c;

    float w0 = 0.f, w1 = 0.f, w2 = 0.f;
#pragma unroll
    for (int d = 3; d >= 1; d--) {
        int tau = t0 - d;
        float s = 0.f;
        if (tau >= 0) {
            s = bfx;
            const float* cr = crow + tau * 16;
#pragma unroll
            for (int k = 0; k < 16; k++) s = fmaf(cr[k], w[k], s);
        }
        if (d == 3) w0 = s; else if (d == 2) w1 = s; else w2 = s;
    }
    for (int t = t0; t < t0 + 78; t++) {
        const float* cr = crow + t * 16;
        float w3 = bfx;
#pragma unroll
        for (int k = 0; k < 16; k++) w3 = fmaf(cr[k], w[k], w3);
        float a = fmaf(k0, w0, fmaf(k1, w1, fmaf(k2, w2, fmaf(k3, w3, cbv))));
        out[(size_t)t * CDIM] = siluf(a);
        w0 = w1; w1 = w2; w2 = w3;
    }
}

// dt head columns: dtv = softplus(...), ev = -exp(A_log)*dtv  (= log dA)
__global__ void k_dt(const float* __restrict__ chk, const float* __restrict__ Wf,
                     const float* __restrict__ bf, const float* __restrict__ A_log,
                     const float* __restrict__ dt_bias,
                     float* __restrict__ dtv, float* __restrict__ ev) {
    int id = blockIdx.x * 256 + threadIdx.x;
    if (id >= NROWS * NH) return;
    int row = id >> 3, h = id & 7;
    const float* cr = chk + (size_t)row * 16;
    float s = bf[DIN + CDIM + h];
#pragma unroll
    for (int k = 0; k < 16; k++) s = fmaf(cr[k], Wf[k * DIP + DIN + CDIM + h], s);
    s += dt_bias[h];
    float sp = (s > 20.f) ? s : log1pf(__expf(s));
    dtv[id] = sp;
    ev[id] = -__expf(A_log[h]) * sp;
}

// within-chunk inclusive prefix of ev: one wave per (b,chunk,head) segment
__global__ __launch_bounds__(256) void k_ecum(const float* __restrict__ ev,
        float* __restrict__ ecum) {
    int s = blockIdx.x * 4 + (threadIdx.x >> 6);
    int lane = threadIdx.x & 63;
    int h = s & 7;
    int cb = s >> 3;
    int c = cb % NCHK, b = cb / NCHK;
    int r0 = b * LSEQ + c * TCH;
    float v = 0.f;
    if (lane < TCH) v = ev[(size_t)(r0 + lane) * NH + h];
#pragma unroll
    for (int off = 1; off < 64; off <<= 1) {
        float u = __shfl_up(v, off);
        if (lane >= off) v += u;
    }
    if (lane < TCH) ecum[(size_t)(r0 + lane) * NH + h] = v;
}

// G[t][s] = C_t . B_s per (b,chunk).  grid (13, 64), 256 thr.
__global__ __launch_bounds__(256) void k_gmat(const float* __restrict__ xBCc,
        float* __restrict__ Gm) {
    int c = blockIdx.x, b = blockIdx.y;
    int tid = threadIdx.x;
    int bs = b * LSEQ;
    __shared__ __align__(16) float sBC[TCH * 132];   // [t][0..63]=B, [t][64..127]=C
#pragma unroll
    for (int j = 0; j < 6; j++) {
        int g = j * 256 + tid;
        int f = g * 4;
        int t = f >> 7, col = f & 127;
        float4 v = *(const float4*)(xBCc + (size_t)(bs + c * TCH + t) * CDIM + 512 + col);
        *(float4*)&sBC[t * 132 + col] = v;
    }
    __syncthreads();
    int t0 = (tid >> 4) * 3, s0 = (tid & 15) * 3;
    float acc[3][3];
#pragma unroll
    for (int i = 0; i < 3; i++)
#pragma unroll
        for (int j = 0; j < 3; j++) acc[i][j] = 0.f;
    for (int k = 0; k < 64; k++) {
        float c0 = sBC[(t0 + 0) * 132 + 64 + k];
        float c1 = sBC[(t0 + 1) * 132 + 64 + k];
        float c2 = sBC[(t0 + 2) * 132 + 64 + k];
        float b0 = sBC[(s0 + 0) * 132 + k];
        float b1 = sBC[(s0 + 1) * 132 + k];
        float b2 = sBC[(s0 + 2) * 132 + k];
        acc[0][0] = fmaf(c0, b0, acc[0][0]); acc[0][1] = fmaf(c0, b1, acc[0][1]); acc[0][2] = fmaf(c0, b2, acc[0][2]);
        acc[1][0] = fmaf(c1, b0, acc[1][0]); acc[1][1] = fmaf(c1, b1, acc[1][1]); acc[1][2] = fmaf(c1, b2, acc[1][2]);
        acc[2][0] = fmaf(c2, b0, acc[2][0]); acc[2][1] = fmaf(c2, b1, acc[2][1]); acc[2][2] = fmaf(c2, b2, acc[2][2]);
    }
    size_t gb = (size_t)(b * NCHK + c) * (TCH * TCH);
#pragma unroll
    for (int i = 0; i < 3; i++)
#pragma unroll
        for (int j = 0; j < 3; j++)
            Gm[gb + (t0 + i) * TCH + (s0 + j)] = acc[i][j];
}

// intra-chunk: Y = M @ X + dsk*X, M[t][s] = exp(E[t]-E[s])*dt_s*G[t][s] (s<=t)
__global__ __launch_bounds__(256) void k_intra(const float* __restrict__ xBCc,
        const float* __restrict__ Gm, const float* __restrict__ dtv,
        const float* __restrict__ ecum, const float* __restrict__ Dskip,
        float* __restrict__ ysb) {
    int c = blockIdx.x, head = blockIdx.y, b = blockIdx.z;
    int tid = threadIdx.x;
    int bs = b * LSEQ;
    int r0 = bs + c * TCH;
    __shared__ __align__(16) float sX[TCH * 64];
    __shared__ float sM[TCH * TCH];
    __shared__ float sE[TCH], sdt[TCH];

#pragma unroll
    for (int j = 0; j < 3; j++) {
        int g = j * 256 + tid;
        int f = g * 4;
        int t = f >> 6, col = f & 63;
        float4 v = *(const float4*)(xBCc + (size_t)(r0 + t) * CDIM + head * HD + col);
        *(float4*)&sX[t * 64 + col] = v;
    }
    if (tid < TCH) {
        sE[tid] = ecum[(size_t)(r0 + tid) * NH + head];
        sdt[tid] = dtv[(size_t)(r0 + tid) * NH + head];
    }
    __syncthreads();
    size_t gb = (size_t)(b * NCHK + c) * (TCH * TCH);
#pragma unroll
    for (int k = 0; k < 9; k++) {
        int id = k * 256 + tid;
        int t = id / TCH, s = id - t * TCH;
        float g = Gm[gb + id];
        sM[id] = (s <= t) ? __expf(sE[t] - sE[s]) * sdt[s] * g : 0.f;
    }
    __syncthreads();

    int t0 = (tid >> 4) * 3, p4 = (tid & 15) * 4;
    float4 a0 = {0,0,0,0}, a1 = {0,0,0,0}, a2 = {0,0,0,0};
    for (int s = 0; s < TCH; s++) {
        float m0 = sM[(t0 + 0) * TCH + s];
        float m1 = sM[(t0 + 1) * TCH + s];
        float m2 = sM[(t0 + 2) * TCH + s];
        float4 xv = *(const float4*)&sX[s * 64 + p4];
        a0.x = fmaf(m0, xv.x, a0.x); a0.y = fmaf(m0, xv.y, a0.y);
        a0.z = fmaf(m0, xv.z, a0.z); a0.w = fmaf(m0, xv.w, a0.w);
        a1.x = fmaf(m1, xv.x, a1.x); a1.y = fmaf(m1, xv.y, a1.y);
        a1.z = fmaf(m1, xv.z, a1.z); a1.w = fmaf(m1, xv.w, a1.w);
        a2.x = fmaf(m2, xv.x, a2.x); a2.y = fmaf(m2, xv.y, a2.y);
        a2.z = fmaf(m2, xv.z, a2.z); a2.w = fmaf(m2, xv.w, a2.w);
    }
    float dsk = Dskip[head];
    float4 accs[3] = {a0, a1, a2};
#pragma unroll
    for (int i = 0; i < 3; i++) {
        float4 xo = *(const float4*)&sX[(t0 + i) * 64 + p4];
        float4 o;
        o.x = fmaf(dsk, xo.x, accs[i].x);
        o.y = fmaf(dsk, xo.y, accs[i].y);
        o.z = fmaf(dsk, xo.z, accs[i].z);
        o.w = fmaf(dsk, xo.w, accs[i].w);
        *(float4*)&ysb[(size_t)(r0 + t0 + i) * DIN + head * HD + p4] = o;
    }
}

// inter-chunk carry + y-correction, full HD per block (r4 structure + reg prefetch).
// grid (8, 64); 256 thr. State 4p x 4n per thread; y-GEMM 3t x 4p.
__global__ __launch_bounds__(256, 2) void k_carry(const float* __restrict__ xBCc,
        const float* __restrict__ dtv, const float* __restrict__ ecum,
        float* __restrict__ ysb) {
    int head = blockIdx.x, b = blockIdx.y;
    int tid = threadIdx.x;
    int bs = b * LSEQ;
    __shared__ __align__(16) float sX[TCH * 64];      // 12 KB
    __shared__ __align__(16) float sB[TCH * 64];      // 12 KB
    __shared__ __align__(16) float sC[TCH * 68];      // 12.75 KB (pad: C-row reads)
    __shared__ __align__(16) float hbuf[64 * 68];     // 17 KB [n][p] pad
    __shared__ float sW[TCH], sDt[TCH];

    int i4 = (tid >> 4) * 4;   // p (state)
    int j4 = (tid & 15) * 4;   // n (state)
    int t0 = (tid >> 4) * 3;   // t (y-GEMM)
    int p4 = (tid & 15) * 4;   // p (y-GEMM)

    float h[4][4];
#pragma unroll
    for (int i = 0; i < 4; i++)
#pragma unroll
        for (int j = 0; j < 4; j++) h[i][j] = 0.f;

    float4 rX[3], rB[3], rC[3];
    float rEc = 0.f, rDt = 0.f, rEcL = 0.f;

#define CARRY_ISSUE(cc)                                                             \
    {                                                                               \
        int r0i = bs + (cc) * TCH;                                                  \
        _Pragma("unroll")                                                           \
        for (int jj = 0; jj < 3; jj++) {                                            \
            int g = jj * 256 + tid; int f = 4 * g; int t = f >> 6; int col = f & 63;\
            const float* rowp = xBCc + (size_t)(r0i + t) * CDIM;                    \
            rX[jj] = *(const float4*)(rowp + head * HD + col);                      \
            rB[jj] = *(const float4*)(rowp + 512 + col);                            \
            rC[jj] = *(const float4*)(rowp + 576 + col);                            \
        }                                                                           \
        if (tid < TCH) { rEc = ecum[(size_t)(r0i + tid) * NH + head];               \
                         rDt = dtv[(size_t)(r0i + tid) * NH + head]; }              \
        rEcL = ecum[(size_t)(r0i + TCH - 1) * NH + head];                           \
    }

    CARRY_ISSUE(0);
    for (int c = 0; c < NCHK; c++) {
        int r0 = bs + c * TCH;
        __syncthreads();                       // prev compute done; LDS reusable
        float eL = __expf(rEcL);
#pragma unroll
        for (int jj = 0; jj < 3; jj++) {
            int g = jj * 256 + tid; int f = 4 * g; int t = f >> 6; int col = f & 63;
            *(float4*)&sX[t * 64 + col] = rX[jj];
            *(float4*)&sB[t * 64 + col] = rB[jj];
            *(float4*)&sC[t * 68 + col] = rC[jj];
        }
        if (tid < TCH) { sW[tid] = __expf(rEcL - rEc) * rDt; sDt[tid] = __expf(rEc); }
        // publish h_start (pre-update state)
#pragma unroll
        for (int jj = 0; jj < 4; jj++) {
            float4 v = { h[0][jj], h[1][jj], h[2][jj], h[3][jj] };
            *(float4*)&hbuf[(j4 + jj) * 68 + i4] = v;
        }
        __syncthreads();
        if (c + 1 < NCHK) CARRY_ISSUE(c + 1);  // in flight during compute

        if (c > 0) {
            float4 a0 = {0,0,0,0}, a1 = {0,0,0,0}, a2 = {0,0,0,0};
            for (int k = 0; k < 64; k++) {
                float c0 = sC[(t0 + 0) * 68 + k];
                float c1 = sC[(t0 + 1) * 68 + k];
                float c2 = sC[(t0 + 2) * 68 + k];
                float4 hv = *(const float4*)&hbuf[k * 68 + p4];
                a0.x = fmaf(c0, hv.x, a0.x); a0.y = fmaf(c0, hv.y, a0.y);
                a0.z = fmaf(c0, hv.z, a0.z); a0.w = fmaf(c0, hv.w, a0.w);
                a1.x = fmaf(c1, hv.x, a1.x); a1.y = fmaf(c1, hv.y, a1.y);
                a1.z = fmaf(c1, hv.z, a1.z); a1.w = fmaf(c1, hv.w, a1.w);
                a2.x = fmaf(c2, hv.x, a2.x); a2.y = fmaf(c2, hv.y, a2.y);
                a2.z = fmaf(c2, hv.z, a2.z); a2.w = fmaf(c2, hv.w, a2.w);
            }
            float4 as[3] = {a0, a1, a2};
#pragma unroll
            for (int i = 0; i < 3; i++) {
                float d = sDt[t0 + i];
                float* yp = ysb + (size_t)(r0 + t0 + i) * DIN + head * HD + p4;
                float4 y = *(const float4*)yp;
                y.x = fmaf(d, as[i].x, y.x);
                y.y = fmaf(d, as[i].y, y.y);
                y.z = fmaf(d, as[i].z, y.z);
                y.w = fmaf(d, as[i].w, y.w);
                *(float4*)yp = y;
            }
        }

        // state update: h = eL*h + sum_s sW[s] * X[s][p] * B[s][n]
#pragma unroll
        for (int i = 0; i < 4; i++)
#pragma unroll
            for (int j = 0; j < 4; j++) h[i][j] *= eL;
        for (int s = 0; s < TCH; s++) {
            float w = sW[s];
            float4 xv = *(const float4*)&sX[s * 64 + i4];
            float4 bv = *(const float4*)&sB[s * 64 + j4];
            float x0 = w * xv.x, x1 = w * xv.y, x2 = w * xv.z, x3 = w * xv.w;
            h[0][0] = fmaf(x0, bv.x, h[0][0]); h[0][1] = fmaf(x0, bv.y, h[0][1]);
            h[0][2] = fmaf(x0, bv.z, h[0][2]); h[0][3] = fmaf(x0, bv.w, h[0][3]);
            h[1][0] = fmaf(x1, bv.x, h[1][0]); h[1][1] = fmaf(x1, bv.y, h[1][1]);
            h[1][2] = fmaf(x1, bv.z, h[1][2]); h[1][3] = fmaf(x1, bv.w, h[1][3]);
            h[2][0] = fmaf(x2, bv.x, h[2][0]); h[2][1] = fmaf(x2, bv.y, h[2][1]);
            h[2][2] = fmaf(x2, bv.z, h[2][2]); h[2][3] = fmaf(x2, bv.w, h[2][3]);
            h[3][0] = fmaf(x3, bv.x, h[3][0]); h[3][1] = fmaf(x3, bv.y, h[3][1]);
            h[3][2] = fmaf(x3, bv.z, h[3][2]); h[3][3] = fmaf(x3, bv.w, h[3][3]);
        }
    }
#undef CARRY_ISSUE
}

// gate (recompute z, reg weights) + RMSNorm + fused out_proj@proj + scatter.
__global__ __launch_bounds__(256) void k_gate(const float* __restrict__ chk,
        const float* __restrict__ Wf, const float* __restrict__ bf,
        const float* __restrict__ ysb, const float* __restrict__ norm_w,
        const float* __restrict__ Wop, const float* __restrict__ bop,
        float* __restrict__ feat) {
    int row0 = blockIdx.x * 8;
    int tid = threadIdx.x;
    __shared__ float sy[512];
    __shared__ float sred[256];
    __shared__ float swave[4];
    int c1 = tid, c2 = tid + 256;
    float wz1[16], wz2[16];
#pragma unroll
    for (int k = 0; k < 16; k++) {
        wz1[k] = Wf[k * DIP + c1];
        wz2[k] = Wf[k * DIP + c2];
    }
    float zb1 = bf[c1], zb2 = bf[c2];
    float nw1 = norm_w[c1], nw2 = norm_w[c2];
    int o = tid & 15, kg = tid >> 4;
    int wid = tid >> 6, lane = tid & 63;
    for (int r = 0; r < 8; r++) {
        int row = row0 + r;
        const float4* cp = (const float4*)(chk + (size_t)row * 16);
        float4 cA = cp[0], cB = cp[1], cC = cp[2], cD = cp[3];
        float cv[16] = {cA.x,cA.y,cA.z,cA.w, cB.x,cB.y,cB.z,cB.w,
                        cC.x,cC.y,cC.z,cC.w, cD.x,cD.y,cD.z,cD.w};
        float z1 = zb1, z2 = zb2;
#pragma unroll
        for (int k = 0; k < 16; k++) {
            z1 = fmaf(cv[k], wz1[k], z1);
            z2 = fmaf(cv[k], wz2[k], z2);
        }
        float y1 = ysb[(size_t)row * DIN + c1] * siluf(z1);
        float y2 = ysb[(size_t)row * DIN + c2] * siluf(z2);
        float ss = y1 * y1 + y2 * y2;
#pragma unroll
        for (int off = 32; off >= 1; off >>= 1) ss += __shfl_xor(ss, off);
        if (lane == 0) swave[wid] = ss;
        __syncthreads();
        float tot = swave[0] + swave[1] + swave[2] + swave[3];
        float scale = 1.f / sqrtf(tot * (1.f / 512.f) + 1e-5f);
        sy[c1] = y1 * scale * nw1;
        sy[c2] = y2 * scale * nw2;
        __syncthreads();
        float ps = 0.f;
#pragma unroll
        for (int j = 0; j < 32; j++) {
            int k = kg * 32 + j;
            ps = fmaf(sy[k], Wop[k * 16 + o], ps);
        }
        sred[kg * 16 + o] = ps;
        __syncthreads();
        if (tid < 16) {
            float s = bop[tid];
#pragma unroll
            for (int g = 0; g < 16; g++) s += sred[g * 16 + tid];
            int bb = row / LSEQ, t = row % LSEQ;
            feat[(size_t)(bb * NPG_C + t) * 16 + tid] = s;
        }
    }
}

// build per-dst adjacency: cnt (int) + slot list of src ids
__global__ void k_scatter(const int* __restrict__ src, const int* __restrict__ dst,
                          int* __restrict__ cnt, int* __restrict__ slots) {
    int e = blockIdx.x * 256 + threadIdx.x;
    if (e >= N_EDGES_C) return;
    int d = dst[e];
    int pos = atomicAdd(&cnt[d], 1);
    if (pos < CAP) slots[(size_t)d * CAP + pos] = src[e];
}

// dst-centric aggregate, 1-deep pipelined feat prefetch
__global__ __launch_bounds__(128) void k_agg(const int* __restrict__ cnt,
        const int* __restrict__ slots, const float* __restrict__ feat,
        const float* __restrict__ Wm, const float* __restrict__ bm,
        float* __restrict__ agg) {
    int d = blockIdx.x, c = threadIdx.x;
    int deg = cnt[d];
    if (deg > CAP) deg = CAP;
    float w[16];
#pragma unroll
    for (int k = 0; k < 16; k++) w[k] = Wm[k * 128 + c];
    float bmv = bm[c];
    float acc = 0.f;
    const int* sl = slots + (size_t)d * CAP;
    float4 f0, f1, f2, f3;
    if (deg > 0) {
        int s = sl[0];
        const float4* fr = (const float4*)(feat + (size_t)s * 16);
        f0 = fr[0]; f1 = fr[1]; f2 = fr[2]; f3 = fr[3];
    }
    for (int e = 0; e < deg; e++) {
        float4 g0 = f0, g1 = f1, g2 = f2, g3 = f3;
        if (e + 1 < deg) {
            int s = sl[e + 1];
            const float4* fr = (const float4*)(feat + (size_t)s * 16);
            f0 = fr[0]; f1 = fr[1]; f2 = fr[2]; f3 = fr[3];
        }
        float m = bmv;
        m = fmaf(g0.x, w[0],  m); m = fmaf(g0.y, w[1],  m);
        m = fmaf(g0.z, w[2],  m); m = fmaf(g0.w, w[3],  m);
        m = fmaf(g1.x, w[4],  m); m = fmaf(g1.y, w[5],  m);
        m = fmaf(g1.z, w[6],  m); m = fmaf(g1.w, w[7],  m);
        m = fmaf(g2.x, w[8],  m); m = fmaf(g2.y, w[9],  m);
        m = fmaf(g2.z, w[10], m); m = fmaf(g2.w, w[11], m);
        m = fmaf(g3.x, w[12], m); m = fmaf(g3.y, w[13], m);
        m = fmaf(g3.z, w[14], m); m = fmaf(g3.w, w[15], m);
        acc += fmaxf(m, 0.f);
    }
    agg[(size_t)d * 128 + c] = acc;
}

// node update MLP + output head, 32 nodes per block
#define UNB 32
__global__ __launch_bounds__(256) void k_upd2(const float* __restrict__ feat,
        const float* __restrict__ agg, const float* __restrict__ Wu,
        const float* __restrict__ bu, const float* __restrict__ Wo2,
        const float* __restrict__ bo2, float* __restrict__ out) {
    int g0 = blockIdx.x * UNB;
    int tid = threadIdx.x;
    __shared__ __align__(16) float sin_[UNB][144];
    __shared__ float part[4][16][2];
    for (int w = tid; w < UNB * 144; w += 256) {
        int node = w / 144, k = w - node * 144;
        sin_[node][k] = (k < 16) ? feat[(size_t)(g0 + node) * 16 + k]
                                 : agg[(size_t)(g0 + node) * 128 + (k - 16)];
    }
    __syncthreads();
    int rr = tid >> 7, c = tid & 127;
    float acc[16];
#pragma unroll
    for (int nn = 0; nn < 16; nn++) acc[nn] = 0.f;
    for (int k0 = 0; k0 < 144; k0 += 4) {
        float wu0 = Wu[(k0 + 0) * 128 + c];
        float wu1 = Wu[(k0 + 1) * 128 + c];
        float wu2 = Wu[(k0 + 2) * 128 + c];
        float wu3 = Wu[(k0 + 3) * 128 + c];
#pragma unroll
        for (int nn = 0; nn < 16; nn++) {
            float4 s4 = *(const float4*)&sin_[rr * 16 + nn][k0];
            acc[nn] = fmaf(s4.x, wu0, acc[nn]);
            acc[nn] = fmaf(s4.y, wu1, acc[nn]);
            acc[nn] = fmaf(s4.z, wu2, acc[nn]);
            acc[nn] = fmaf(s4.w, wu3, acc[nn]);
        }
    }
    float buc = bu[c];
    float w0 = Wo2[c * 2], w1 = Wo2[c * 2 + 1];
    float p[16][2];
#pragma unroll
    for (int nn = 0; nn < 16; nn++) {
        float hh = fmaxf(acc[nn] + buc, 0.f);
        p[nn][0] = hh * w0;
        p[nn][1] = hh * w1;
    }
#pragma unroll
    for (int off = 1; off < 64; off <<= 1) {
#pragma unroll
        for (int nn = 0; nn < 16; nn++) {
            p[nn][0] += __shfl_xor(p[nn][0], off);
            p[nn][1] += __shfl_xor(p[nn][1], off);
        }
    }
    int wv = tid >> 6;
    if ((tid & 63) == 0) {
#pragma unroll
        for (int nn = 0; nn < 16; nn++) {
            part[wv][nn][0] = p[nn][0];
            part[wv][nn][1] = p[nn][1];
        }
    }
    __syncthreads();
    if (tid < 64) {
        int o = tid & 1, nn = (tid >> 1) & 15, r2 = tid >> 5;
        float v = part[r2 * 2 + 0][nn][o] + part[r2 * 2 + 1][nn][o] + bo2[o];
        out[(size_t)(g0 + r2 * 16 + nn) * 2 + o] = v;
    }
}

extern "C" void kernel_launch(void* const* d_in, const int* in_sizes, int n_in,
                              void* d_out, int out_size, void* d_ws, size_t ws_size,
                              hipStream_t stream) {
    const float* node_inputs = (const float*)d_in[0];
    const int*   src_ids     = (const int*)d_in[1];
    const int*   dst_ids     = (const int*)d_in[2];
    const float* W_embed     = (const float*)d_in[3];
    const float* b_embed     = (const float*)d_in[4];
    const float* W_in        = (const float*)d_in[5];
    const float* b_in        = (const float*)d_in[6];
    const float* conv_w      = (const float*)d_in[7];
    const float* conv_b      = (const float*)d_in[8];
    const float* A_log       = (const float*)d_in[9];
    const float* dt_bias     = (const float*)d_in[10];
    const float* D_skip      = (const float*)d_in[11];
    const float* norm_w      = (const float*)d_in[12];
    const float* W_outp      = (const float*)d_in[13];
    const float* b_outp      = (const float*)d_in[14];
    const float* W_proj      = (const float*)d_in[15];
    const float* b_proj      = (const float*)d_in[16];
    const float* W_msg       = (const float*)d_in[17];
    const float* b_msg       = (const float*)d_in[18];
    const float* W_upd       = (const float*)d_in[19];
    const float* b_upd       = (const float*)d_in[20];
    const float* W_out       = (const float*)d_in[21];
    const float* b_out       = (const float*)d_in[22];

    float* ws   = (float*)d_ws;
    float* chk  = ws + OFF_CHK;
    float* Wf   = ws + OFF_WF;
    float* bf   = ws + OFF_BF;
    float* Wop  = ws + OFF_WOP;
    float* bop  = ws + OFF_BOP;
    float* xBCc = ws + OFF_XBC;
    float* dtv  = ws + OFF_DTV;
    float* ev   = ws + OFF_EV;
    float* ecum = ws + OFF_ECUM;
    float* ysb  = ws + OFF_YS;
    float* feat = ws + OFF_FEAT;
    float* agg  = ws + OFF_AGG;
    float* Gm   = ws + OFF_AGG;            // aliases agg (dead until k_agg)
    int*   slots = (int*)(ws + OFF_XBC);   // aliases xBCc (dead after k_carry)
    int*   cnt   = (int*)(ws + OFF_DTV);   // aliases dtv  (dead after k_carry)
    float* out  = (float*)d_out;

    hipMemsetAsync(feat, 0, (size_t)N_NODES_C * 16 * 4, stream);

    k_gather<<<(NROWS * 16 + 255) / 256, 256, 0, stream>>>(node_inputs, chk);
    k_fusew<<<(16 * DIP + DIP + DIN * 16 + 16 + 255) / 256, 256, 0, stream>>>(
        W_embed, b_embed, W_in, b_in, W_outp, b_outp, W_proj, b_proj, Wf, bf, Wop, bop);
    k_conv<<<dim3(2, 8, BATCH_C), 320, 0, stream>>>(chk, Wf, bf, conv_w, conv_b, xBCc);
    k_dt<<<(NROWS * NH + 255) / 256, 256, 0, stream>>>(chk, Wf, bf, A_log, dt_bias, dtv, ev);
    k_ecum<<<(BATCH_C * NCHK * NH) / 4, 256, 0, stream>>>(ev, ecum);
    k_gmat<<<dim3(NCHK, BATCH_C), 256, 0, stream>>>(xBCc, Gm);
    k_intra<<<dim3(NCHK, NH, BATCH_C), 256, 0, stream>>>(xBCc, Gm, dtv, ecum, D_skip, ysb);
    k_carry<<<dim3(NH, BATCH_C), 256, 0, stream>>>(xBCc, dtv, ecum, ysb);
    k_gate<<<NROWS / 8, 256, 0, stream>>>(chk, Wf, bf, ysb, norm_w, Wop, bop, feat);
    hipMemsetAsync(cnt, 0, (size_t)N_NODES_C * 4, stream);
    k_scatter<<<(N_EDGES_C + 255) / 256, 256, 0, stream>>>(src_ids, dst_ids, cnt, slots);
    k_agg<<<N_NODES_C, 128, 0, stream>>>(cnt, slots, feat, W_msg, b_msg, agg);
    k_upd2<<<N_NODES_C / UNB, 256, 0, stream>>>(feat, agg, W_upd, b_upd, W_out, b_out, out);
}